// Round 5
// baseline (458.356 us; speedup 1.0000x reference)
//
#include <hip/hip_runtime.h>

#define DIM   1024
#define NG    8
#define NBLK  32
#define TPB   512                 // 8 waves/block
#define WAVES (TPB / 64)
#define RPW   4                   // rows per wave: NBLK*WAVES*RPW = 1024
#define ROWS_PER_BLK (WAVES * RPW)
#define RADIUS 1.45f              // bound on spectral radius (semicircle: ~1.414)
#define TTOL   1e-3f
#define MAXM   40

typedef unsigned long long u64;

// Self-timed message passing: every published complex value is two 8-byte
// words (re|tag) (im|tag) stored with relaxed agent-scope 64-bit atomics
// (LLC-coherent, per-8B atomic). The tag (= global phase number `pub`) makes
// the data its own readiness flag: a reader accepts a slot only when BOTH
// halves carry tag == pub. No vmcnt drain, no flags, no block barrier.
//
// Buffer reuse safety (2 buffers, parity ping-pong, monotone tags): a wave
// stores phase t+2 only after it consumed ALL of phase t+1; all of t+1
// exists only after every wave consumed all of t. Hence tag t+2 cannot
// appear anywhere while any wave still polls for t. Load->store ordering is
// by data dependence: each stored y uses every loaded v element.
//
// d_ws arrives poisoned 0xAA -> initial tags are 0xAAAAAAAA, never equal to
// a valid pub (1..~120): no initialization dispatch needed.

__device__ __forceinline__ u64 pack(float v, unsigned tag) {
  union { float f; unsigned u; } c; c.f = v;
  return ((u64)tag << 32) | (u64)c.u;
}
__device__ __forceinline__ float unpackf(u64 x) {
  union { unsigned u; float f; } c; c.u = (unsigned)x;
  return c.f;
}

__global__ __launch_bounds__(TPB) void qsim_kernel(
    const float* __restrict__ feat,
    const float* __restrict__ theta,
    const float* __restrict__ gens,
    float*       __restrict__ out,
    u64*         __restrict__ vbufA,
    u64*         __restrict__ vbufB)
{
  const int tid  = threadIdx.x;
  const int lane = tid & 63;
  const int wid  = tid >> 6;                       // 0..7
  const int bid  = blockIdx.x;
  const int rowbase = bid * ROWS_PER_BLK + wid * RPW;

  __shared__ float red[WAVES];

  // ---- gate-0 G rows first: HBM latency overlaps the norm phase ----
  float a[RPW][16];
  #pragma unroll
  for (int rr = 0; rr < RPW; ++rr) {
    const float* Gr = gens + (size_t)(rowbase + rr) * DIM;
    #pragma unroll
    for (int p = 0; p < 16; ++p) a[rr][p] = Gr[p * 64 + lane];
  }

  {
    float f0 = feat[tid], f1 = feat[tid + TPB];
    float s = f0 * f0 + f1 * f1;
    #pragma unroll
    for (int mm = 1; mm < 64; mm <<= 1) s += __shfl_xor(s, mm);
    if (lane == 0) red[wid] = s;
  }
  __syncthreads();                                  // init only
  float tot = 0.f;
  #pragma unroll
  for (int i = 0; i < WAVES; ++i) tot += red[i];
  const float inv = 1.0f / sqrtf(tot);

  float pr[RPW], pi[RPW];
  #pragma unroll
  for (int rr = 0; rr < RPW; ++rr) {
    pr[rr] = feat[rowbase + rr] * inv;
    pi[rr] = 0.f;
  }

  unsigned pub = 0;   // completed publishes (lock-stepped across all waves)

  // lanes 0..3 store rows rowbase+0..3 as (re|tag)(im|tag); no drain, no flag
  auto publish = [&](const float* xr, const float* xi) {
    ++pub;
    u64* dst = (pub & 1) ? vbufA : vbufB;
    float sr = xr[0], si = xi[0];
    if (lane == 1) { sr = xr[1]; si = xi[1]; }
    if (lane == 2) { sr = xr[2]; si = xi[2]; }
    if (lane == 3) { sr = xr[3]; si = xi[3]; }
    if (lane < RPW) {
      const int row = rowbase + lane;
      __hip_atomic_store(dst + row * 2,     pack(sr, pub),
                         __ATOMIC_RELAXED, __HIP_MEMORY_SCOPE_AGENT);
      __hip_atomic_store(dst + row * 2 + 1, pack(si, pub),
                         __ATOMIC_RELAXED, __HIP_MEMORY_SCOPE_AGENT);
    }
  };

  publish(pr, pi);                                  // psi_0  (pub -> 1)

  for (int g = 0; g < NG; ++g) {
    const float th = theta[g];
    const float aa = fabsf(th) * RADIUS;
    int   m = 0; float t = 1.f;
    while (m < MAXM && t > TTOL) { ++m; t *= aa / (float)m; }
    // m >= 1; identical on every wave/block -> uniform publish count

    float accr[RPW], acci[RPW];
    #pragma unroll
    for (int rr = 0; rr < RPW; ++rr) { accr[rr] = pr[rr]; acci[rr] = pi[rr]; }
    float cr = 1.f, ci = 0.f;                       // (-i*th)^k / k!

    for (int k = 1; k <= m; ++k) {
      const u64* vsrc = (pub & 1) ? vbufA : vbufB;  // buffer of phase `pub`
      float yr[RPW] = {0, 0, 0, 0}, yi[RPW] = {0, 0, 0, 0};

      // ---- self-timed consume: poll pending slots, FMA on acceptance ----
      unsigned pend = 0xFFFFu;
      while (pend) {
        u64 lo[16], hi[16];
        const unsigned snap = pend;
        #pragma unroll
        for (int p = 0; p < 16; ++p) {
          if ((snap >> p) & 1u) {
            const int idx = (p * 64 + lane) * 2;
            lo[p] = __hip_atomic_load(vsrc + idx,     __ATOMIC_RELAXED,
                                      __HIP_MEMORY_SCOPE_AGENT);
            hi[p] = __hip_atomic_load(vsrc + idx + 1, __ATOMIC_RELAXED,
                                      __HIP_MEMORY_SCOPE_AGENT);
          }
        }
        #pragma unroll
        for (int p = 0; p < 16; ++p) {
          if ((snap >> p) & 1u) {
            if ((unsigned)(lo[p] >> 32) == pub &&
                (unsigned)(hi[p] >> 32) == pub) {
              const float vr = unpackf(lo[p]);
              const float vi = unpackf(hi[p]);
              #pragma unroll
              for (int rr = 0; rr < RPW; ++rr) {
                yr[rr] = fmaf(a[rr][p], vr, yr[rr]);
                yi[rr] = fmaf(a[rr][p], vi, yi[rr]);
              }
              pend &= ~(1u << p);
            }
          }
        }
      }

      // ---- full-wave butterfly reduce (all lanes end with row sums) ----
      #pragma unroll
      for (int mm = 1; mm < 64; mm <<= 1) {
        #pragma unroll
        for (int rr = 0; rr < RPW; ++rr) {
          yr[rr] += __shfl_xor(yr[rr], mm);
          yi[rr] += __shfl_xor(yi[rr], mm);
        }
      }

      const float fk  = th / (float)k;
      const float ncr =  ci * fk;
      const float nci = -cr * fk;
      cr = ncr; ci = nci;
      #pragma unroll
      for (int rr = 0; rr < RPW; ++rr) {
        accr[rr] += cr * yr[rr] - ci * yi[rr];
        acci[rr] += cr * yi[rr] + ci * yr[rr];
      }

      const bool last = (k == m);
      if (last && g == NG - 1) break;               // nobody consumes it
      if (last) publish(accr, acci);
      else      publish(yr, yi);
      if (last) {
        // next gate's G rows; completes while the next poll loop spins
        const float* Gg = gens + (size_t)(g + 1) * DIM * DIM;
        #pragma unroll
        for (int rr = 0; rr < RPW; ++rr) {
          const float* Gr = Gg + (size_t)(rowbase + rr) * DIM;
          #pragma unroll
          for (int p = 0; p < 16; ++p) a[rr][p] = Gr[p * 64 + lane];
        }
      }
    }
    #pragma unroll
    for (int rr = 0; rr < RPW; ++rr) { pr[rr] = accr[rr]; pi[rr] = acci[rr]; }
  }

  {
    float o = pr[0] * pr[0] + pi[0] * pi[0];
    if (lane == 1) o = pr[1] * pr[1] + pi[1] * pi[1];
    if (lane == 2) o = pr[2] * pr[2] + pi[2] * pi[2];
    if (lane == 3) o = pr[3] * pr[3] + pi[3] * pi[3];
    if (lane < RPW) out[rowbase + lane] = o;
  }
}

extern "C" void kernel_launch(void* const* d_in, const int* in_sizes, int n_in,
                              void* d_out, int out_size, void* d_ws, size_t ws_size,
                              hipStream_t stream) {
  const float* feat  = (const float*)d_in[0];
  const float* theta = (const float*)d_in[1];
  const float* gens  = (const float*)d_in[2];
  float* out = (float*)d_out;

  // two self-timed buffers: 1024 rows x 2 u64 (re|tag, im|tag) = 16 KB each.
  // 0xAA poison = tag 0xAAAAAAAA, never a valid phase -> no init needed.
  u64* vbufA = (u64*)((char*)d_ws + 1024);
  u64* vbufB = (u64*)((char*)d_ws + 1024 + DIM * 2 * sizeof(u64));

  qsim_kernel<<<dim3(NBLK), dim3(TPB), 0, stream>>>(
      feat, theta, gens, out, vbufA, vbufB);
}

// Round 6
// 335.587 us; speedup vs baseline: 1.3658x; 1.3658x over previous
//
#include <hip/hip_runtime.h>

#define DIM   1024
#define NG    8
#define NBLK  32
#define TPB   512                 // 8 waves/block
#define WAVES (TPB / 64)
#define RPW   4                   // rows per wave: NBLK*WAVES*RPW = 1024
#define ROWS_PER_BLK (WAVES * RPW)
#define NWAVE (NBLK * WAVES)      // 256 waves, one flag each
#define RADIUS 1.45f              // bound on spectral radius (semicircle: ~1.414)
#define TTOL   1e-2f              // measured: prob-err ~= 1e-3 * TTOL (R5: 9.5e-7 @ 1e-3)
#define MAXM   40

typedef unsigned long long u64;
union f2u { float2 f; u64 u; };

// R4 mechanism (measured best: ~3.5us/phase), trimmed:
//  - per-WAVE flags (256 x u32, unpadded = 16 cache lines): publish is
//    data-store -> s_waitcnt(0) (stores ACKed at LLC) -> own flag store.
//    No LDS atomic, no block aggregation on the critical path.
//  - readiness test is wrap-safe signed compare (int)(flag - pub) >= 0:
//    the 0xAA poison (0xAAAAAAAA) reads "not ready", so NO memset dispatch.
//  - poll: 4 loads/lane covers all 256 flags; __all ballot.
//  - 2-buffer parity ping-pong; monotone flags give the anti-dependency
//    (a wave publishes t+2 only after consuming t+1, which exists only
//    after every wave consumed t).

__global__ __launch_bounds__(TPB) void qsim_kernel(
    const float* __restrict__ feat,
    const float* __restrict__ theta,
    const float* __restrict__ gens,
    float*       __restrict__ out,
    u64*         __restrict__ vbufA,
    u64*         __restrict__ vbufB,
    unsigned*    __restrict__ flags)
{
  const int tid  = threadIdx.x;
  const int lane = tid & 63;
  const int wid  = tid >> 6;                       // 0..7
  const int bid  = blockIdx.x;
  const int wv   = bid * WAVES + wid;              // 0..255
  const int rowbase = wv * RPW;

  __shared__ float red[WAVES];

  // ---- gate-0 G rows first: HBM latency overlaps the norm phase ----
  float a[RPW][16];
  #pragma unroll
  for (int rr = 0; rr < RPW; ++rr) {
    const float* Gr = gens + (size_t)(rowbase + rr) * DIM;
    #pragma unroll
    for (int p = 0; p < 16; ++p) a[rr][p] = Gr[p * 64 + lane];
  }

  {
    float f0 = feat[tid], f1 = feat[tid + TPB];
    float s = f0 * f0 + f1 * f1;
    #pragma unroll
    for (int mm = 1; mm < 64; mm <<= 1) s += __shfl_xor(s, mm);
    if (lane == 0) red[wid] = s;
  }
  __syncthreads();                                  // init only
  float tot = 0.f;
  #pragma unroll
  for (int i = 0; i < WAVES; ++i) tot += red[i];
  const float inv = 1.0f / sqrtf(tot);

  float pr[RPW], pi[RPW];
  #pragma unroll
  for (int rr = 0; rr < RPW; ++rr) {
    pr[rr] = feat[rowbase + rr] * inv;
    pi[rr] = 0.f;
  }

  unsigned pub = 0;   // completed publishes (lock-stepped across all waves)

  auto publish = [&](const float* xr, const float* xi) {
    ++pub;
    u64* dst = (pub & 1) ? vbufA : vbufB;
    float sr = xr[0], si = xi[0];
    if (lane == 1) { sr = xr[1]; si = xi[1]; }
    if (lane == 2) { sr = xr[2]; si = xi[2]; }
    if (lane == 3) { sr = xr[3]; si = xi[3]; }
    if (lane < RPW) {
      f2u x; x.f = make_float2(sr, si);
      __hip_atomic_store(dst + rowbase + lane, x.u,
                         __ATOMIC_RELAXED, __HIP_MEMORY_SCOPE_AGENT);
    }
    __builtin_amdgcn_sched_barrier(0);
    __builtin_amdgcn_s_waitcnt(0);    // wave's data stores ACKed at the LLC
    __builtin_amdgcn_sched_barrier(0);
    if (lane == 0) {
      __hip_atomic_store(flags + wv, pub,
                         __ATOMIC_RELAXED, __HIP_MEMORY_SCOPE_AGENT);
    }
  };

  auto wait_all = [&]() {
    for (;;) {
      unsigned f0 = __hip_atomic_load(flags + lane,       __ATOMIC_RELAXED,
                                      __HIP_MEMORY_SCOPE_AGENT);
      unsigned f1 = __hip_atomic_load(flags + lane + 64,  __ATOMIC_RELAXED,
                                      __HIP_MEMORY_SCOPE_AGENT);
      unsigned f2 = __hip_atomic_load(flags + lane + 128, __ATOMIC_RELAXED,
                                      __HIP_MEMORY_SCOPE_AGENT);
      unsigned f3 = __hip_atomic_load(flags + lane + 192, __ATOMIC_RELAXED,
                                      __HIP_MEMORY_SCOPE_AGENT);
      // wrap-safe monotone >=; 0xAAAAAAAA poison reads not-ready
      bool ok = ((int)(f0 - pub) >= 0) & ((int)(f1 - pub) >= 0) &
                ((int)(f2 - pub) >= 0) & ((int)(f3 - pub) >= 0);
      if (__all(ok)) break;
    }
  };

  publish(pr, pi);                                  // psi_0  (pub -> 1)

  for (int g = 0; g < NG; ++g) {
    const float th = theta[g];
    const float aa = fabsf(th) * RADIUS;
    int   m = 0; float t = 1.f;
    while (m < MAXM && t > TTOL) { ++m; t *= aa / (float)m; }
    // m >= 1; identical on every wave/block -> uniform publish count

    float accr[RPW], acci[RPW];
    #pragma unroll
    for (int rr = 0; rr < RPW; ++rr) { accr[rr] = pr[rr]; acci[rr] = pi[rr]; }
    float cr = 1.f, ci = 0.f;                       // (-i*th)^k / k!

    for (int k = 1; k <= m; ++k) {
      wait_all();
      const u64* vsrc = (pub & 1) ? vbufA : vbufB;  // buffer of phase `pub`
      float vr[16], vi[16];
      #pragma unroll
      for (int p = 0; p < 16; ++p) {
        f2u x;
        x.u = __hip_atomic_load(vsrc + p * 64 + lane,
                                __ATOMIC_RELAXED, __HIP_MEMORY_SCOPE_AGENT);
        vr[p] = x.f.x; vi[p] = x.f.y;
      }
      float yr[RPW] = {0, 0, 0, 0}, yi[RPW] = {0, 0, 0, 0};
      #pragma unroll
      for (int p = 0; p < 16; ++p) {
        #pragma unroll
        for (int rr = 0; rr < RPW; ++rr) {
          yr[rr] = fmaf(a[rr][p], vr[p], yr[rr]);
          yi[rr] = fmaf(a[rr][p], vi[p], yi[rr]);
        }
      }
      #pragma unroll
      for (int mm = 1; mm < 64; mm <<= 1) {
        #pragma unroll
        for (int rr = 0; rr < RPW; ++rr) {
          yr[rr] += __shfl_xor(yr[rr], mm);
          yi[rr] += __shfl_xor(yi[rr], mm);
        }
      }

      const bool last = (k == m);
      if (!last) publish(yr, yi);   // stores fly before the tail VALU below

      const float fk  = th / (float)k;
      const float ncr =  ci * fk;
      const float nci = -cr * fk;
      cr = ncr; ci = nci;
      #pragma unroll
      for (int rr = 0; rr < RPW; ++rr) {
        accr[rr] += cr * yr[rr] - ci * yi[rr];
        acci[rr] += cr * yi[rr] + ci * yr[rr];
      }

      if (last) {
        if (g == NG - 1) break;                     // nobody consumes it
        publish(accr, acci);                        // psi_{g+1}
        // next gate's G rows; completes while the next wait_all spins
        const float* Gg = gens + (size_t)(g + 1) * DIM * DIM;
        #pragma unroll
        for (int rr = 0; rr < RPW; ++rr) {
          const float* Gr = Gg + (size_t)(rowbase + rr) * DIM;
          #pragma unroll
          for (int p = 0; p < 16; ++p) a[rr][p] = Gr[p * 64 + lane];
        }
      }
    }
    #pragma unroll
    for (int rr = 0; rr < RPW; ++rr) { pr[rr] = accr[rr]; pi[rr] = acci[rr]; }
  }

  {
    float o = pr[0] * pr[0] + pi[0] * pi[0];
    if (lane == 1) o = pr[1] * pr[1] + pi[1] * pi[1];
    if (lane == 2) o = pr[2] * pr[2] + pi[2] * pi[2];
    if (lane == 3) o = pr[3] * pr[3] + pi[3] * pi[3];
    if (lane < RPW) out[rowbase + lane] = o;
  }
}

extern "C" void kernel_launch(void* const* d_in, const int* in_sizes, int n_in,
                              void* d_out, int out_size, void* d_ws, size_t ws_size,
                              hipStream_t stream) {
  const float* feat  = (const float*)d_in[0];
  const float* theta = (const float*)d_in[1];
  const float* gens  = (const float*)d_in[2];
  float* out = (float*)d_out;

  // layout: flags[256] (1KB) | vbufA (8KB) | vbufB (8KB)
  // no memset: signed wrap-compare treats 0xAA poison as "not ready"
  unsigned* flags = (unsigned*)d_ws;
  u64* vbufA = (u64*)((char*)d_ws + 1024);
  u64* vbufB = (u64*)((char*)d_ws + 1024 + DIM * sizeof(u64));

  qsim_kernel<<<dim3(NBLK), dim3(TPB), 0, stream>>>(
      feat, theta, gens, out, vbufA, vbufB, flags);
}

// Round 7
// 239.592 us; speedup vs baseline: 1.9131x; 1.4007x over previous
//
#include <hip/hip_runtime.h>

#define DIM   1024
#define NG    8
#define NBLK  32
#define TPB   512                 // 8 waves/block
#define WAVES (TPB / 64)
#define RPW   4                   // rows per wave: NBLK*WAVES*RPW = 1024
#define ROWS_PER_BLK (WAVES * RPW)
#define RADIUS 1.45f              // bound on spectral radius (semicircle: ~1.414)
#define TTOL   1e-2f              // measured: prob-err ~= 1e-3 * TTOL (R5/R6)
#define MAXM   40
#define FSTRIDE 16                // flags padded to 64B (16 u32) each

typedef unsigned long long u64;
union f2u { float2 f; u64 u; };

// R4 mechanism verbatim (measured best per-phase among low-traffic schemes):
//   per term, each wave stores its 4 rows (agent relaxed, LLC-coherent)
//   -> s_waitcnt(0) drains the wave's stores to the coherence point
//   -> lane0 LDS atomicAdd on the block's monotone publish counter
//   -> the block's 8th publisher release-stores flags[bid] (own 64B line)
//   -> every wave polls all 32 flags with ONE 32-lane load + __all ballot.
// (R6 taught us: more polled lines / more loads per poll iteration regress
//  per-phase 3.5 -> 5.6 us. Keep polled-line count at 32, padded.)
//
// Changes vs R4:
//  - TTOL 1e-2 (R6-measured absmax 1.5e-5, 9x under threshold)
//  - gate 0, term 1 consumes psi_0 rebuilt locally from feat*inv -> the
//    initial publish phase is deleted.
//  - flag readiness = wrap-safe (int)(f - pub) >= 0, so the 0xAA poison
//    (0xAAAAAAAA) reads "not ready": no memset dispatch needed.

__global__ __launch_bounds__(TPB) void qsim_kernel(
    const float* __restrict__ feat,
    const float* __restrict__ theta,
    const float* __restrict__ gens,
    float*       __restrict__ out,
    u64*         __restrict__ vbuf0,
    u64*         __restrict__ vbuf1,
    unsigned*    __restrict__ flags)
{
  const int tid  = threadIdx.x;
  const int lane = tid & 63;
  const int wid  = tid >> 6;                       // 0..7
  const int bid  = blockIdx.x;
  const int rowbase = bid * ROWS_PER_BLK + wid * RPW;

  __shared__ float red[WAVES];
  __shared__ unsigned wdone;                       // monotone publish counter

  // ---- gate-0 G rows first: HBM latency overlaps the norm phase ----
  float a[RPW][16];
  #pragma unroll
  for (int rr = 0; rr < RPW; ++rr) {
    const float* Gr = gens + (size_t)(rowbase + rr) * DIM;
    #pragma unroll
    for (int p = 0; p < 16; ++p) a[rr][p] = Gr[p * 64 + lane];
  }

  if (tid == 0) wdone = 0;
  {
    float f0 = feat[tid], f1 = feat[tid + TPB];
    float s = f0 * f0 + f1 * f1;
    #pragma unroll
    for (int mm = 1; mm < 64; mm <<= 1) s += __shfl_xor(s, mm);
    if (lane == 0) red[wid] = s;
  }
  __syncthreads();                                  // init only
  float tot = 0.f;
  #pragma unroll
  for (int i = 0; i < WAVES; ++i) tot += red[i];
  const float inv = 1.0f / sqrtf(tot);

  float pr[RPW], pi[RPW];
  #pragma unroll
  for (int rr = 0; rr < RPW; ++rr) {
    pr[rr] = feat[rowbase + rr] * inv;
    pi[rr] = 0.f;
  }

  unsigned pub = 0;   // completed publishes (lock-stepped across all waves)

  auto publish = [&](const float* xr, const float* xi) {
    float sr = xr[0], si = xi[0];
    if (lane == 1) { sr = xr[1]; si = xi[1]; }
    if (lane == 2) { sr = xr[2]; si = xi[2]; }
    if (lane == 3) { sr = xr[3]; si = xi[3]; }
    u64* dst = ((pub + 1) & 1) ? vbuf1 : vbuf0;
    if (lane < RPW) {
      f2u x; x.f = make_float2(sr, si);
      __hip_atomic_store(dst + rowbase + lane, x.u,
                         __ATOMIC_RELAXED, __HIP_MEMORY_SCOPE_AGENT);
    }
    __builtin_amdgcn_sched_barrier(0);
    __builtin_amdgcn_s_waitcnt(0);    // wave's data stores at the LLC now
    __builtin_amdgcn_sched_barrier(0);
    ++pub;
    if (lane == 0) {
      unsigned old = atomicAdd(&wdone, 1u);         // LDS, monotone
      if (old == WAVES * pub - 1) {                 // block's last publisher
        __hip_atomic_store(flags + bid * FSTRIDE, pub,
                           __ATOMIC_RELEASE, __HIP_MEMORY_SCOPE_AGENT);
      }
    }
  };

  auto wait_all = [&]() {
    for (;;) {
      unsigned f = (lane < NBLK)
        ? __hip_atomic_load(flags + lane * FSTRIDE, __ATOMIC_RELAXED,
                            __HIP_MEMORY_SCOPE_AGENT)
        : pub;
      // wrap-safe monotone >=; 0xAAAAAAAA poison reads "not ready"
      if (__all((int)(f - pub) >= 0)) break;
    }
  };

  for (int g = 0; g < NG; ++g) {
    const float th = theta[g];
    const float aa = fabsf(th) * RADIUS;
    int   m = 0; float t = 1.f;
    while (m < MAXM && t > TTOL) { ++m; t *= aa / (float)m; }
    // m >= 1; identical on every wave/block -> uniform publish count

    float accr[RPW], acci[RPW];
    #pragma unroll
    for (int rr = 0; rr < RPW; ++rr) { accr[rr] = pr[rr]; acci[rr] = pi[rr]; }
    float cr = 1.f, ci = 0.f;                       // (-i*th)^k / k!

    for (int k = 1; k <= m; ++k) {
      float vr[16], vi[16];
      if (g == 0 && k == 1) {
        // psi_0 rebuilt locally: no publish/wait phase needed
        #pragma unroll
        for (int p = 0; p < 16; ++p) {
          vr[p] = feat[p * 64 + lane] * inv;
          vi[p] = 0.f;
        }
      } else {
        wait_all();
        const u64* vsrc = (pub & 1) ? vbuf1 : vbuf0;  // buffer of phase pub
        #pragma unroll
        for (int p = 0; p < 16; ++p) {
          f2u x;
          x.u = __hip_atomic_load(vsrc + p * 64 + lane,
                                  __ATOMIC_RELAXED, __HIP_MEMORY_SCOPE_AGENT);
          vr[p] = x.f.x; vi[p] = x.f.y;
        }
      }
      float yr[RPW] = {0, 0, 0, 0}, yi[RPW] = {0, 0, 0, 0};
      #pragma unroll
      for (int p = 0; p < 16; ++p) {
        #pragma unroll
        for (int rr = 0; rr < RPW; ++rr) {
          yr[rr] = fmaf(a[rr][p], vr[p], yr[rr]);
          yi[rr] = fmaf(a[rr][p], vi[p], yi[rr]);
        }
      }
      #pragma unroll
      for (int mm = 1; mm < 64; mm <<= 1) {
        #pragma unroll
        for (int rr = 0; rr < RPW; ++rr) {
          yr[rr] += __shfl_xor(yr[rr], mm);
          yi[rr] += __shfl_xor(yi[rr], mm);
        }
      }

      const bool last = (k == m);
      if (!last) publish(yr, yi);   // stores fly before the tail VALU below

      const float fk  = th / (float)k;
      const float ncr =  ci * fk;
      const float nci = -cr * fk;
      cr = ncr; ci = nci;
      #pragma unroll
      for (int rr = 0; rr < RPW; ++rr) {
        accr[rr] += cr * yr[rr] - ci * yi[rr];
        acci[rr] += cr * yi[rr] + ci * yr[rr];
      }

      if (last) {
        if (g == NG - 1) break;                     // nobody consumes it
        publish(accr, acci);                        // psi_{g+1}
        // next gate's G rows; completes while the next wait_all spins
        const float* Gg = gens + (size_t)(g + 1) * DIM * DIM;
        #pragma unroll
        for (int rr = 0; rr < RPW; ++rr) {
          const float* Gr = Gg + (size_t)(rowbase + rr) * DIM;
          #pragma unroll
          for (int p = 0; p < 16; ++p) a[rr][p] = Gr[p * 64 + lane];
        }
      }
    }
    #pragma unroll
    for (int rr = 0; rr < RPW; ++rr) { pr[rr] = accr[rr]; pi[rr] = acci[rr]; }
  }

  {
    float o = pr[0] * pr[0] + pi[0] * pi[0];
    if (lane == 1) o = pr[1] * pr[1] + pi[1] * pi[1];
    if (lane == 2) o = pr[2] * pr[2] + pi[2] * pi[2];
    if (lane == 3) o = pr[3] * pr[3] + pi[3] * pi[3];
    if (lane < RPW) out[rowbase + lane] = o;
  }
}

extern "C" void kernel_launch(void* const* d_in, const int* in_sizes, int n_in,
                              void* d_out, int out_size, void* d_ws, size_t ws_size,
                              hipStream_t stream) {
  const float* feat  = (const float*)d_in[0];
  const float* theta = (const float*)d_in[1];
  const float* gens  = (const float*)d_in[2];
  float* out = (float*)d_out;

  // layout: flags 32 x 64B (2KB) | vbuf0 (8KB) | vbuf1 (8KB)
  // no memset: wrap-safe compare treats the 0xAA poison as "not ready"
  unsigned* flags = (unsigned*)d_ws;
  u64* vbuf0 = (u64*)((char*)d_ws + 2048);
  u64* vbuf1 = (u64*)((char*)d_ws + 2048 + DIM * sizeof(u64));

  qsim_kernel<<<dim3(NBLK), dim3(TPB), 0, stream>>>(
      feat, theta, gens, out, vbuf0, vbuf1, flags);
}

// Round 8
// 189.404 us; speedup vs baseline: 2.4200x; 1.2650x over previous
//
#include <hip/hip_runtime.h>

#define DIM   1024
#define NG    8
#define NBLK  32
#define TPB   512                 // 8 waves/block
#define WAVES (TPB / 64)
#define RPW   4                   // rows per wave: NBLK*WAVES*RPW = 1024
#define ROWS_PER_BLK (WAVES * RPW)
#define SCALE    1.45f            // upper bound on spectral radius (semicircle ~1.414)
#define INVSCALE (1.0f / SCALE)
#define CTOL  2.5e-3f             // stop when 2|J_{m+1}| < 5e-3 (~= Taylor TTOL 1e-2 tail)
#define KMAX  12
#define FSTRIDE 16                // flags padded to 64B (16 u32) each

typedef unsigned long long u64;
union f2u { float2 f; u64 u; };

// Mechanism: R7 verbatim (measured floor ~3.9us/phase).
// Algorithm: Chebyshev instead of Taylor.
//   exp(-i z xh) = J_0(z) + 2 sum_k (-i)^k J_k(z) T_k(xh),  xh = G/SCALE,
//   w_{k+1} = 2 xh w_k - w_{k-1}.  One publish per matvec, same phase
//   structure as Taylor, but m ~ z+4 instead of ~e*z  (47 -> ~29 phases).
// J_k(|z|) via downward Miller recurrence in fp64 (unrolled, registers),
// identical on every wave -> uniform m -> uniform phase count. Coeffs go to
// parity-double-buffered LDS for dynamic-k reads (waves are <=1 gate apart,
// proven by the publish/wait lockstep, so no cross-gate clobber).

__global__ __launch_bounds__(TPB) void qsim_kernel(
    const float* __restrict__ feat,
    const float* __restrict__ theta,
    const float* __restrict__ gens,
    float*       __restrict__ out,
    u64*         __restrict__ vbuf0,
    u64*         __restrict__ vbuf1,
    unsigned*    __restrict__ flags)
{
  const int tid  = threadIdx.x;
  const int lane = tid & 63;
  const int wid  = tid >> 6;                       // 0..7
  const int bid  = blockIdx.x;
  const int rowbase = bid * ROWS_PER_BLK + wid * RPW;

  __shared__ float red[WAVES];
  __shared__ unsigned wdone;                       // monotone publish counter
  __shared__ float Jsh[2][KMAX + 2];               // per-gate-parity coeffs

  // ---- gate-0 G rows first: HBM latency overlaps the norm phase ----
  float a[RPW][16];
  #pragma unroll
  for (int rr = 0; rr < RPW; ++rr) {
    const float* Gr = gens + (size_t)(rowbase + rr) * DIM;
    #pragma unroll
    for (int p = 0; p < 16; ++p) a[rr][p] = Gr[p * 64 + lane];
  }

  if (tid == 0) wdone = 0;
  {
    float f0 = feat[tid], f1 = feat[tid + TPB];
    float s = f0 * f0 + f1 * f1;
    #pragma unroll
    for (int mm = 1; mm < 64; mm <<= 1) s += __shfl_xor(s, mm);
    if (lane == 0) red[wid] = s;
  }
  __syncthreads();                                  // init only
  float tot = 0.f;
  #pragma unroll
  for (int i = 0; i < WAVES; ++i) tot += red[i];
  const float inv = 1.0f / sqrtf(tot);

  float pr[RPW], pi[RPW];
  #pragma unroll
  for (int rr = 0; rr < RPW; ++rr) {
    pr[rr] = feat[rowbase + rr] * inv;
    pi[rr] = 0.f;
  }

  unsigned pub = 0;   // completed publishes (lock-stepped across all waves)

  auto publish = [&](const float* xr, const float* xi) {
    float sr = xr[0], si = xi[0];
    if (lane == 1) { sr = xr[1]; si = xi[1]; }
    if (lane == 2) { sr = xr[2]; si = xi[2]; }
    if (lane == 3) { sr = xr[3]; si = xi[3]; }
    u64* dst = ((pub + 1) & 1) ? vbuf1 : vbuf0;
    if (lane < RPW) {
      f2u x; x.f = make_float2(sr, si);
      __hip_atomic_store(dst + rowbase + lane, x.u,
                         __ATOMIC_RELAXED, __HIP_MEMORY_SCOPE_AGENT);
    }
    __builtin_amdgcn_sched_barrier(0);
    __builtin_amdgcn_s_waitcnt(0);    // wave's data stores at the LLC now
    __builtin_amdgcn_sched_barrier(0);
    ++pub;
    if (lane == 0) {
      unsigned old = atomicAdd(&wdone, 1u);         // LDS, monotone
      if (old == WAVES * pub - 1) {                 // block's last publisher
        __hip_atomic_store(flags + bid * FSTRIDE, pub,
                           __ATOMIC_RELEASE, __HIP_MEMORY_SCOPE_AGENT);
      }
    }
  };

  auto wait_all = [&]() {
    for (;;) {
      unsigned f = (lane < NBLK)
        ? __hip_atomic_load(flags + lane * FSTRIDE, __ATOMIC_RELAXED,
                            __HIP_MEMORY_SCOPE_AGENT)
        : pub;
      // wrap-safe monotone >=; 0xAAAAAAAA poison reads "not ready"
      if (__all((int)(f - pub) >= 0)) break;
    }
  };

  for (int g = 0; g < NG; ++g) {
    // ---- Chebyshev coefficients: J_k(|z|), downward Miller in fp64 ----
    const float  th = theta[g];
    const double z  = (double)th * (double)SCALE;
    const double az = fmax(fabs(z), 1e-6);
    const float  sg = (th < 0.f) ? -1.f : 1.f;      // J_k(z)=sg^k J_k(|z|)

    double bv[19];
    bv[18] = 1e-30;
    bv[17] = (36.0 / az) * 1e-30;
    #pragma unroll
    for (int k = 17; k >= 1; --k)
      bv[k - 1] = (2.0 * (double)k / az) * bv[k] - bv[k + 1];
    double S = bv[0];
    #pragma unroll
    for (int k = 2; k <= 18; k += 2) S += 2.0 * bv[k];
    const double invS = 1.0 / S;

    float* Jc = Jsh[g & 1];
    #pragma unroll
    for (int k = 0; k <= KMAX + 1; ++k) Jc[k] = (float)(bv[k] * invS);

    int m = KMAX; bool found = false;
    #pragma unroll
    for (int k = 1; k <= KMAX; ++k) {
      if (!found && (double)(k + 1) > az &&
          fabs(bv[k + 1] * invS) < (double)CTOL) { m = k; found = true; }
    }
    // m identical on every wave/block -> uniform phase count

    const float J0 = (float)(bv[0] * invS);
    float accr[RPW], acci[RPW];
    float wm1r[RPW], wm1i[RPW], wm2r[RPW], wm2i[RPW];
    #pragma unroll
    for (int rr = 0; rr < RPW; ++rr) {
      accr[rr] = J0 * pr[rr]; acci[rr] = J0 * pi[rr];
      wm1r[rr] = pr[rr];      wm1i[rr] = pi[rr];
      wm2r[rr] = 0.f;         wm2i[rr] = 0.f;
    }

    for (int k = 1; k <= m; ++k) {
      // ---- consume full w_{k-1} ----
      float vr[16], vi[16];
      if (g == 0 && k == 1) {
        // psi_0 rebuilt locally: no publish/wait phase needed
        #pragma unroll
        for (int p = 0; p < 16; ++p) {
          vr[p] = feat[p * 64 + lane] * inv;
          vi[p] = 0.f;
        }
      } else {
        wait_all();
        const u64* vsrc = (pub & 1) ? vbuf1 : vbuf0;  // buffer of phase pub
        #pragma unroll
        for (int p = 0; p < 16; ++p) {
          f2u x;
          x.u = __hip_atomic_load(vsrc + p * 64 + lane,
                                  __ATOMIC_RELAXED, __HIP_MEMORY_SCOPE_AGENT);
          vr[p] = x.f.x; vi[p] = x.f.y;
        }
      }
      const float jk = Jc[k];                       // LDS, dynamic k

      // ---- y = G * w_{k-1} (own rows) ----
      float yr[RPW] = {0, 0, 0, 0}, yi[RPW] = {0, 0, 0, 0};
      #pragma unroll
      for (int p = 0; p < 16; ++p) {
        #pragma unroll
        for (int rr = 0; rr < RPW; ++rr) {
          yr[rr] = fmaf(a[rr][p], vr[p], yr[rr]);
          yi[rr] = fmaf(a[rr][p], vi[p], yi[rr]);
        }
      }
      #pragma unroll
      for (int mm = 1; mm < 64; mm <<= 1) {
        #pragma unroll
        for (int rr = 0; rr < RPW; ++rr) {
          yr[rr] += __shfl_xor(yr[rr], mm);
          yi[rr] += __shfl_xor(yi[rr], mm);
        }
      }

      // ---- w_k = (k==1) ? xh*w_0 : 2*xh*w_{k-1} - w_{k-2}  (own rows) ----
      float wkr[RPW], wki[RPW];
      #pragma unroll
      for (int rr = 0; rr < RPW; ++rr) {
        const float ur = yr[rr] * INVSCALE;
        const float ui = yi[rr] * INVSCALE;
        wkr[rr] = (k == 1) ? ur : fmaf(2.f, ur, -wm2r[rr]);
        wki[rr] = (k == 1) ? ui : fmaf(2.f, ui, -wm2i[rr]);
      }

      const bool last = (k == m);
      if (!last) publish(wkr, wki);   // stores fly before the tail VALU below

      // ---- acc += c_k * w_k,  c_k = 2*(-i*sg)^k * J_k(|z|) ----
      const float j2  = 2.f * jk;
      const float sj2 = sg * j2;
      switch (k & 3) {
        case 0:
          #pragma unroll
          for (int rr = 0; rr < RPW; ++rr) {
            accr[rr] = fmaf(j2, wkr[rr], accr[rr]);
            acci[rr] = fmaf(j2, wki[rr], acci[rr]);
          } break;
        case 1:
          #pragma unroll
          for (int rr = 0; rr < RPW; ++rr) {
            accr[rr] = fmaf( sj2, wki[rr], accr[rr]);
            acci[rr] = fmaf(-sj2, wkr[rr], acci[rr]);
          } break;
        case 2:
          #pragma unroll
          for (int rr = 0; rr < RPW; ++rr) {
            accr[rr] = fmaf(-j2, wkr[rr], accr[rr]);
            acci[rr] = fmaf(-j2, wki[rr], acci[rr]);
          } break;
        default:
          #pragma unroll
          for (int rr = 0; rr < RPW; ++rr) {
            accr[rr] = fmaf(-sj2, wki[rr], accr[rr]);
            acci[rr] = fmaf( sj2, wkr[rr], acci[rr]);
          } break;
      }

      if (last) {
        if (g < NG - 1) {
          publish(accr, acci);                      // psi_{g+1}
          // next gate's G rows; completes while the next wait_all spins
          const float* Gg = gens + (size_t)(g + 1) * DIM * DIM;
          #pragma unroll
          for (int rr = 0; rr < RPW; ++rr) {
            const float* Gr = Gg + (size_t)(rowbase + rr) * DIM;
            #pragma unroll
            for (int p = 0; p < 16; ++p) a[rr][p] = Gr[p * 64 + lane];
          }
        }
      } else {
        #pragma unroll
        for (int rr = 0; rr < RPW; ++rr) {
          wm2r[rr] = wm1r[rr]; wm2i[rr] = wm1i[rr];
          wm1r[rr] = wkr[rr];  wm1i[rr] = wki[rr];
        }
      }
    }
    #pragma unroll
    for (int rr = 0; rr < RPW; ++rr) { pr[rr] = accr[rr]; pi[rr] = acci[rr]; }
  }

  {
    float o = pr[0] * pr[0] + pi[0] * pi[0];
    if (lane == 1) o = pr[1] * pr[1] + pi[1] * pi[1];
    if (lane == 2) o = pr[2] * pr[2] + pi[2] * pi[2];
    if (lane == 3) o = pr[3] * pr[3] + pi[3] * pi[3];
    if (lane < RPW) out[rowbase + lane] = o;
  }
}

extern "C" void kernel_launch(void* const* d_in, const int* in_sizes, int n_in,
                              void* d_out, int out_size, void* d_ws, size_t ws_size,
                              hipStream_t stream) {
  const float* feat  = (const float*)d_in[0];
  const float* theta = (const float*)d_in[1];
  const float* gens  = (const float*)d_in[2];
  float* out = (float*)d_out;

  // layout: flags 32 x 64B (2KB) | vbuf0 (8KB) | vbuf1 (8KB)
  // no memset: wrap-safe compare treats the 0xAA poison as "not ready"
  unsigned* flags = (unsigned*)d_ws;
  u64* vbuf0 = (u64*)((char*)d_ws + 2048);
  u64* vbuf1 = (u64*)((char*)d_ws + 2048 + DIM * sizeof(u64));

  qsim_kernel<<<dim3(NBLK), dim3(TPB), 0, stream>>>(
      feat, theta, gens, out, vbuf0, vbuf1, flags);
}

// Round 9
// 188.617 us; speedup vs baseline: 2.4301x; 1.0042x over previous
//
#include <hip/hip_runtime.h>

#define DIM   1024
#define NG    8
#define NBLK  32
#define TPB   512                 // 8 waves/block
#define WAVES (TPB / 64)
#define RPW   4                   // rows per wave: NBLK*WAVES*RPW = 1024
#define ROWS_PER_BLK (WAVES * RPW)
#define SCALE    1.45f            // upper bound on spectral radius (semicircle ~1.414)
#define INVSCALE (1.0f / SCALE)
#define CTOL  2.5e-3f             // stop when 2|J_{m+1}| < 5e-3 (measured absmax 3e-5)
#define KMAX  12
#define FSTRIDE 16                // flags padded to 64B (16 u32) each

typedef unsigned long long u64;
union f2u { float2 f; u64 u; };

// Mechanism: R7/R8 publish path + two fixes from R8's counters:
//  - k-loop fully unrolled (constant k): Chebyshev coeffs jc[k] stay in
//    REGISTERS -> the all-thread same-address LDS writes (43008 bank
//    conflicts in R8) are gone entirely.
//  - designated poller: only wave 0 of each block polls the 32 flag lines
//    (32 pollers instead of 256 -> less read-storm against flag writers);
//    it bumps an LDS monotone word; sibling waves spin on LDS (~50ns
//    quantum). Data loads stay agent-scope (LLC-coherent) so spinners read
//    fresh data without ever touching the flag lines (same guarantee R4+
//    relied on: ordering via publish-side drains, freshness via sc1 loads).

__global__ __launch_bounds__(TPB) void qsim_kernel(
    const float* __restrict__ feat,
    const float* __restrict__ theta,
    const float* __restrict__ gens,
    float*       __restrict__ out,
    u64*         __restrict__ vbuf0,
    u64*         __restrict__ vbuf1,
    unsigned*    __restrict__ flags)
{
  const int tid  = threadIdx.x;
  const int lane = tid & 63;
  const int wid  = tid >> 6;                       // 0..7
  const int bid  = blockIdx.x;
  const int rowbase = bid * ROWS_PER_BLK + wid * RPW;

  __shared__ float red[WAVES];
  __shared__ unsigned wdone;                       // monotone publish counter
  __shared__ unsigned ready;                       // monotone wake word

  // ---- gate-0 G rows first: HBM latency overlaps the norm phase ----
  float a[RPW][16];
  #pragma unroll
  for (int rr = 0; rr < RPW; ++rr) {
    const float* Gr = gens + (size_t)(rowbase + rr) * DIM;
    #pragma unroll
    for (int p = 0; p < 16; ++p) a[rr][p] = Gr[p * 64 + lane];
  }

  if (tid == 0) { wdone = 0; ready = 0; }
  {
    float f0 = feat[tid], f1 = feat[tid + TPB];
    float s = f0 * f0 + f1 * f1;
    #pragma unroll
    for (int mm = 1; mm < 64; mm <<= 1) s += __shfl_xor(s, mm);
    if (lane == 0) red[wid] = s;
  }
  __syncthreads();                                  // init only
  float tot = 0.f;
  #pragma unroll
  for (int i = 0; i < WAVES; ++i) tot += red[i];
  const float inv = 1.0f / sqrtf(tot);

  float pr[RPW], pi[RPW];
  #pragma unroll
  for (int rr = 0; rr < RPW; ++rr) {
    pr[rr] = feat[rowbase + rr] * inv;
    pi[rr] = 0.f;
  }

  unsigned pub = 0;   // completed publishes (lock-stepped across all waves)

  auto publish = [&](const float* xr, const float* xi) {
    float sr = xr[0], si = xi[0];
    if (lane == 1) { sr = xr[1]; si = xi[1]; }
    if (lane == 2) { sr = xr[2]; si = xi[2]; }
    if (lane == 3) { sr = xr[3]; si = xi[3]; }
    u64* dst = ((pub + 1) & 1) ? vbuf1 : vbuf0;
    if (lane < RPW) {
      f2u x; x.f = make_float2(sr, si);
      __hip_atomic_store(dst + rowbase + lane, x.u,
                         __ATOMIC_RELAXED, __HIP_MEMORY_SCOPE_AGENT);
    }
    __builtin_amdgcn_sched_barrier(0);
    __builtin_amdgcn_s_waitcnt(0);    // wave's data stores at the LLC now
    __builtin_amdgcn_sched_barrier(0);
    ++pub;
    if (lane == 0) {
      unsigned old = atomicAdd(&wdone, 1u);         // LDS, monotone
      if (old == WAVES * pub - 1) {                 // block's last publisher
        __hip_atomic_store(flags + bid * FSTRIDE, pub,
                           __ATOMIC_RELEASE, __HIP_MEMORY_SCOPE_AGENT);
      }
    }
  };

  auto wait_all = [&]() {
    if (wid == 0) {
      for (;;) {
        unsigned f = (lane < NBLK)
          ? __hip_atomic_load(flags + lane * FSTRIDE, __ATOMIC_RELAXED,
                              __HIP_MEMORY_SCOPE_AGENT)
          : pub;
        // wrap-safe monotone >=; 0xAAAAAAAA poison reads "not ready"
        if (__all((int)(f - pub) >= 0)) break;
      }
      if (lane == 0)
        __hip_atomic_store(&ready, pub, __ATOMIC_RELAXED,
                           __HIP_MEMORY_SCOPE_WORKGROUP);
    } else {
      while ((int)(__hip_atomic_load(&ready, __ATOMIC_RELAXED,
                                     __HIP_MEMORY_SCOPE_WORKGROUP) - pub) < 0) {
      }
    }
  };

  for (int g = 0; g < NG; ++g) {
    // ---- Chebyshev coefficients: J_k(|z|), downward Miller in fp64 ----
    const float  th = theta[g];
    const double z  = (double)th * (double)SCALE;
    const double az = fmax(fabs(z), 1e-6);
    const float  sg = (th < 0.f) ? -1.f : 1.f;      // J_k(z)=sg^k J_k(|z|)

    double bv[19];
    bv[18] = 1e-30;
    bv[17] = (36.0 / az) * 1e-30;
    #pragma unroll
    for (int k = 17; k >= 1; --k)
      bv[k - 1] = (2.0 * (double)k / az) * bv[k] - bv[k + 1];
    double S = bv[0];
    #pragma unroll
    for (int k = 2; k <= 18; k += 2) S += 2.0 * bv[k];
    const double invS = 1.0 / S;

    // coeffs to float REGISTERS (constant indices only from here on)
    float jc[KMAX + 2];
    #pragma unroll
    for (int k = 0; k <= KMAX + 1; ++k) jc[k] = (float)(bv[k] * invS);

    int m = KMAX; bool found = false;
    #pragma unroll
    for (int k = 1; k <= KMAX; ++k) {
      if (!found && (double)(k + 1) > az &&
          fabs(bv[k + 1] * invS) < (double)CTOL) { m = k; found = true; }
    }
    // m identical on every wave/block -> uniform phase count

    float accr[RPW], acci[RPW];
    float wm1r[RPW], wm1i[RPW], wm2r[RPW], wm2i[RPW];
    #pragma unroll
    for (int rr = 0; rr < RPW; ++rr) {
      accr[rr] = jc[0] * pr[rr]; acci[rr] = jc[0] * pi[rr];
      wm1r[rr] = pr[rr];         wm1i[rr] = pi[rr];
      wm2r[rr] = 0.f;            wm2i[rr] = 0.f;
    }

    #pragma unroll
    for (int k = 1; k <= KMAX; ++k) {               // fully unrolled
      if (k > m) break;

      // ---- consume full w_{k-1} ----
      float vr[16], vi[16];
      if (g == 0 && k == 1) {
        // psi_0 rebuilt locally: no publish/wait phase needed
        #pragma unroll
        for (int p = 0; p < 16; ++p) {
          vr[p] = feat[p * 64 + lane] * inv;
          vi[p] = 0.f;
        }
      } else {
        wait_all();
        const u64* vsrc = (pub & 1) ? vbuf1 : vbuf0;  // buffer of phase pub
        #pragma unroll
        for (int p = 0; p < 16; ++p) {
          f2u x;
          x.u = __hip_atomic_load(vsrc + p * 64 + lane,
                                  __ATOMIC_RELAXED, __HIP_MEMORY_SCOPE_AGENT);
          vr[p] = x.f.x; vi[p] = x.f.y;
        }
      }

      // ---- y = G * w_{k-1} (own rows) ----
      float yr[RPW] = {0, 0, 0, 0}, yi[RPW] = {0, 0, 0, 0};
      #pragma unroll
      for (int p = 0; p < 16; ++p) {
        #pragma unroll
        for (int rr = 0; rr < RPW; ++rr) {
          yr[rr] = fmaf(a[rr][p], vr[p], yr[rr]);
          yi[rr] = fmaf(a[rr][p], vi[p], yi[rr]);
        }
      }
      #pragma unroll
      for (int mm = 1; mm < 64; mm <<= 1) {
        #pragma unroll
        for (int rr = 0; rr < RPW; ++rr) {
          yr[rr] += __shfl_xor(yr[rr], mm);
          yi[rr] += __shfl_xor(yi[rr], mm);
        }
      }

      // ---- w_k = (k==1) ? xh*w_0 : 2*xh*w_{k-1} - w_{k-2}  (own rows) ----
      float wkr[RPW], wki[RPW];
      #pragma unroll
      for (int rr = 0; rr < RPW; ++rr) {
        const float ur = yr[rr] * INVSCALE;
        const float ui = yi[rr] * INVSCALE;
        wkr[rr] = (k == 1) ? ur : fmaf(2.f, ur, -wm2r[rr]);
        wki[rr] = (k == 1) ? ui : fmaf(2.f, ui, -wm2i[rr]);
      }

      const bool last = (k == m);
      if (!last) publish(wkr, wki);   // stores fly before the tail VALU below

      // ---- acc += c_k * w_k,  c_k = 2*(-i*sg)^k * J_k(|z|) ----
      {
        const float j2  = 2.f * jc[k];              // register (constant k)
        const float sj2 = sg * j2;
        if ((k & 3) == 0) {
          #pragma unroll
          for (int rr = 0; rr < RPW; ++rr) {
            accr[rr] = fmaf(j2, wkr[rr], accr[rr]);
            acci[rr] = fmaf(j2, wki[rr], acci[rr]);
          }
        } else if ((k & 3) == 1) {
          #pragma unroll
          for (int rr = 0; rr < RPW; ++rr) {
            accr[rr] = fmaf( sj2, wki[rr], accr[rr]);
            acci[rr] = fmaf(-sj2, wkr[rr], acci[rr]);
          }
        } else if ((k & 3) == 2) {
          #pragma unroll
          for (int rr = 0; rr < RPW; ++rr) {
            accr[rr] = fmaf(-j2, wkr[rr], accr[rr]);
            acci[rr] = fmaf(-j2, wki[rr], acci[rr]);
          }
        } else {
          #pragma unroll
          for (int rr = 0; rr < RPW; ++rr) {
            accr[rr] = fmaf(-sj2, wki[rr], accr[rr]);
            acci[rr] = fmaf( sj2, wkr[rr], acci[rr]);
          }
        }
      }

      if (last) {
        if (g < NG - 1) {
          publish(accr, acci);                      // psi_{g+1}
          // next gate's G rows; completes while the next wait_all spins
          const float* Gg = gens + (size_t)(g + 1) * DIM * DIM;
          #pragma unroll
          for (int rr = 0; rr < RPW; ++rr) {
            const float* Gr = Gg + (size_t)(rowbase + rr) * DIM;
            #pragma unroll
            for (int p = 0; p < 16; ++p) a[rr][p] = Gr[p * 64 + lane];
          }
        }
      } else {
        #pragma unroll
        for (int rr = 0; rr < RPW; ++rr) {
          wm2r[rr] = wm1r[rr]; wm2i[rr] = wm1i[rr];
          wm1r[rr] = wkr[rr];  wm1i[rr] = wki[rr];
        }
      }
    }
    #pragma unroll
    for (int rr = 0; rr < RPW; ++rr) { pr[rr] = accr[rr]; pi[rr] = acci[rr]; }
  }

  {
    float o = pr[0] * pr[0] + pi[0] * pi[0];
    if (lane == 1) o = pr[1] * pr[1] + pi[1] * pi[1];
    if (lane == 2) o = pr[2] * pr[2] + pi[2] * pi[2];
    if (lane == 3) o = pr[3] * pr[3] + pi[3] * pi[3];
    if (lane < RPW) out[rowbase + lane] = o;
  }
}

extern "C" void kernel_launch(void* const* d_in, const int* in_sizes, int n_in,
                              void* d_out, int out_size, void* d_ws, size_t ws_size,
                              hipStream_t stream) {
  const float* feat  = (const float*)d_in[0];
  const float* theta = (const float*)d_in[1];
  const float* gens  = (const float*)d_in[2];
  float* out = (float*)d_out;

  // layout: flags 32 x 64B (2KB) | vbuf0 (8KB) | vbuf1 (8KB)
  // no memset: wrap-safe compare treats the 0xAA poison as "not ready"
  unsigned* flags = (unsigned*)d_ws;
  u64* vbuf0 = (u64*)((char*)d_ws + 2048);
  u64* vbuf1 = (u64*)((char*)d_ws + 2048 + DIM * sizeof(u64));

  qsim_kernel<<<dim3(NBLK), dim3(TPB), 0, stream>>>(
      feat, theta, gens, out, vbuf0, vbuf1, flags);
}

// Round 10
// 161.695 us; speedup vs baseline: 2.8347x; 1.1665x over previous
//
#include <hip/hip_runtime.h>

#define DIM   1024
#define NG    8
#define NBLK  64
#define TPB   512                 // 8 waves/block
#define WAVES (TPB / 64)
#define RPW   2                   // rows per wave: NBLK*WAVES*RPW = 1024
#define ROWS_PER_BLK (WAVES * RPW)
#define SCALE    1.45f            // upper bound on spectral radius (semicircle ~1.414)
#define INVSCALE (1.0f / SCALE)
#define CTOL  5e-3f               // stop when 2|J_{m+1}| < 1e-2 (predicted absmax ~6e-5)
#define KMAX  12
#define FSTRIDE 16                // flags padded to 64B (16 u32) each

typedef unsigned long long u64;
union f2u { float2 f; u64 u; };

// Mechanism: R7/R9 verbatim (measured floor ~2.9us/phase marginal).
// R10 changes attack the OTHER terms in the fitted cost model
// (t = 2.9us * phases + 42us fixed):
//  - NBLK 64 (RPW 2): twice the CUs pull the 33.5MB of G -> fixed G-load
//    term halves (~43 -> ~22us). Poll is still ONE 64-lane load (64 flags).
//  - CTOL 5e-3: ~1 fewer Chebyshev term per gate (measured-linear error
//    map predicts absmax ~6e-5 vs 1.4e-4 threshold).

__global__ __launch_bounds__(TPB) void qsim_kernel(
    const float* __restrict__ feat,
    const float* __restrict__ theta,
    const float* __restrict__ gens,
    float*       __restrict__ out,
    u64*         __restrict__ vbuf0,
    u64*         __restrict__ vbuf1,
    unsigned*    __restrict__ flags)
{
  const int tid  = threadIdx.x;
  const int lane = tid & 63;
  const int wid  = tid >> 6;                       // 0..7
  const int bid  = blockIdx.x;
  const int rowbase = bid * ROWS_PER_BLK + wid * RPW;

  __shared__ float red[WAVES];
  __shared__ unsigned wdone;                       // monotone publish counter
  __shared__ unsigned ready;                       // monotone wake word

  // ---- gate-0 G rows first: HBM latency overlaps the norm phase ----
  float a[RPW][16];
  #pragma unroll
  for (int rr = 0; rr < RPW; ++rr) {
    const float* Gr = gens + (size_t)(rowbase + rr) * DIM;
    #pragma unroll
    for (int p = 0; p < 16; ++p) a[rr][p] = Gr[p * 64 + lane];
  }

  if (tid == 0) { wdone = 0; ready = 0; }
  {
    float f0 = feat[tid], f1 = feat[tid + TPB];
    float s = f0 * f0 + f1 * f1;
    #pragma unroll
    for (int mm = 1; mm < 64; mm <<= 1) s += __shfl_xor(s, mm);
    if (lane == 0) red[wid] = s;
  }
  __syncthreads();                                  // init only
  float tot = 0.f;
  #pragma unroll
  for (int i = 0; i < WAVES; ++i) tot += red[i];
  const float inv = 1.0f / sqrtf(tot);

  float pr[RPW], pi[RPW];
  #pragma unroll
  for (int rr = 0; rr < RPW; ++rr) {
    pr[rr] = feat[rowbase + rr] * inv;
    pi[rr] = 0.f;
  }

  unsigned pub = 0;   // completed publishes (lock-stepped across all waves)

  auto publish = [&](const float* xr, const float* xi) {
    float sr = xr[0], si = xi[0];
    if (lane == 1) { sr = xr[1]; si = xi[1]; }
    u64* dst = ((pub + 1) & 1) ? vbuf1 : vbuf0;
    if (lane < RPW) {
      f2u x; x.f = make_float2(sr, si);
      __hip_atomic_store(dst + rowbase + lane, x.u,
                         __ATOMIC_RELAXED, __HIP_MEMORY_SCOPE_AGENT);
    }
    __builtin_amdgcn_sched_barrier(0);
    __builtin_amdgcn_s_waitcnt(0);    // wave's data stores at the LLC now
    __builtin_amdgcn_sched_barrier(0);
    ++pub;
    if (lane == 0) {
      unsigned old = atomicAdd(&wdone, 1u);         // LDS, monotone
      if (old == WAVES * pub - 1) {                 // block's last publisher
        __hip_atomic_store(flags + bid * FSTRIDE, pub,
                           __ATOMIC_RELEASE, __HIP_MEMORY_SCOPE_AGENT);
      }
    }
  };

  auto wait_all = [&]() {
    if (wid == 0) {
      for (;;) {
        unsigned f = __hip_atomic_load(flags + lane * FSTRIDE,
                                       __ATOMIC_RELAXED,
                                       __HIP_MEMORY_SCOPE_AGENT);
        // wrap-safe monotone >=; 0xAAAAAAAA poison reads "not ready"
        if (__all((int)(f - pub) >= 0)) break;
      }
      if (lane == 0)
        __hip_atomic_store(&ready, pub, __ATOMIC_RELAXED,
                           __HIP_MEMORY_SCOPE_WORKGROUP);
    } else {
      while ((int)(__hip_atomic_load(&ready, __ATOMIC_RELAXED,
                                     __HIP_MEMORY_SCOPE_WORKGROUP) - pub) < 0) {
      }
    }
  };

  for (int g = 0; g < NG; ++g) {
    // ---- Chebyshev coefficients: J_k(|z|), downward Miller in fp64 ----
    const float  th = theta[g];
    const double z  = (double)th * (double)SCALE;
    const double az = fmax(fabs(z), 1e-6);
    const float  sg = (th < 0.f) ? -1.f : 1.f;      // J_k(z)=sg^k J_k(|z|)

    double bv[19];
    bv[18] = 1e-30;
    bv[17] = (36.0 / az) * 1e-30;
    #pragma unroll
    for (int k = 17; k >= 1; --k)
      bv[k - 1] = (2.0 * (double)k / az) * bv[k] - bv[k + 1];
    double S = bv[0];
    #pragma unroll
    for (int k = 2; k <= 18; k += 2) S += 2.0 * bv[k];
    const double invS = 1.0 / S;

    // coeffs to float REGISTERS (constant indices only from here on)
    float jc[KMAX + 2];
    #pragma unroll
    for (int k = 0; k <= KMAX + 1; ++k) jc[k] = (float)(bv[k] * invS);

    int m = KMAX; bool found = false;
    #pragma unroll
    for (int k = 1; k <= KMAX; ++k) {
      if (!found && (double)(k + 1) > az &&
          fabs(bv[k + 1] * invS) < (double)CTOL) { m = k; found = true; }
    }
    // m identical on every wave/block -> uniform phase count

    float accr[RPW], acci[RPW];
    float wm1r[RPW], wm1i[RPW], wm2r[RPW], wm2i[RPW];
    #pragma unroll
    for (int rr = 0; rr < RPW; ++rr) {
      accr[rr] = jc[0] * pr[rr]; acci[rr] = jc[0] * pi[rr];
      wm1r[rr] = pr[rr];         wm1i[rr] = pi[rr];
      wm2r[rr] = 0.f;            wm2i[rr] = 0.f;
    }

    #pragma unroll
    for (int k = 1; k <= KMAX; ++k) {               // fully unrolled
      if (k > m) break;

      // ---- consume full w_{k-1} ----
      float vr[16], vi[16];
      if (g == 0 && k == 1) {
        // psi_0 rebuilt locally: no publish/wait phase needed
        #pragma unroll
        for (int p = 0; p < 16; ++p) {
          vr[p] = feat[p * 64 + lane] * inv;
          vi[p] = 0.f;
        }
      } else {
        wait_all();
        const u64* vsrc = (pub & 1) ? vbuf1 : vbuf0;  // buffer of phase pub
        #pragma unroll
        for (int p = 0; p < 16; ++p) {
          f2u x;
          x.u = __hip_atomic_load(vsrc + p * 64 + lane,
                                  __ATOMIC_RELAXED, __HIP_MEMORY_SCOPE_AGENT);
          vr[p] = x.f.x; vi[p] = x.f.y;
        }
      }

      // ---- y = G * w_{k-1} (own rows) ----
      float yr[RPW] = {0, 0}, yi[RPW] = {0, 0};
      #pragma unroll
      for (int p = 0; p < 16; ++p) {
        #pragma unroll
        for (int rr = 0; rr < RPW; ++rr) {
          yr[rr] = fmaf(a[rr][p], vr[p], yr[rr]);
          yi[rr] = fmaf(a[rr][p], vi[p], yi[rr]);
        }
      }
      #pragma unroll
      for (int mm = 1; mm < 64; mm <<= 1) {
        #pragma unroll
        for (int rr = 0; rr < RPW; ++rr) {
          yr[rr] += __shfl_xor(yr[rr], mm);
          yi[rr] += __shfl_xor(yi[rr], mm);
        }
      }

      // ---- w_k = (k==1) ? xh*w_0 : 2*xh*w_{k-1} - w_{k-2}  (own rows) ----
      float wkr[RPW], wki[RPW];
      #pragma unroll
      for (int rr = 0; rr < RPW; ++rr) {
        const float ur = yr[rr] * INVSCALE;
        const float ui = yi[rr] * INVSCALE;
        wkr[rr] = (k == 1) ? ur : fmaf(2.f, ur, -wm2r[rr]);
        wki[rr] = (k == 1) ? ui : fmaf(2.f, ui, -wm2i[rr]);
      }

      const bool last = (k == m);
      if (!last) publish(wkr, wki);   // stores fly before the tail VALU below

      // ---- acc += c_k * w_k,  c_k = 2*(-i*sg)^k * J_k(|z|) ----
      {
        const float j2  = 2.f * jc[k];              // register (constant k)
        const float sj2 = sg * j2;
        if ((k & 3) == 0) {
          #pragma unroll
          for (int rr = 0; rr < RPW; ++rr) {
            accr[rr] = fmaf(j2, wkr[rr], accr[rr]);
            acci[rr] = fmaf(j2, wki[rr], acci[rr]);
          }
        } else if ((k & 3) == 1) {
          #pragma unroll
          for (int rr = 0; rr < RPW; ++rr) {
            accr[rr] = fmaf( sj2, wki[rr], accr[rr]);
            acci[rr] = fmaf(-sj2, wkr[rr], acci[rr]);
          }
        } else if ((k & 3) == 2) {
          #pragma unroll
          for (int rr = 0; rr < RPW; ++rr) {
            accr[rr] = fmaf(-j2, wkr[rr], accr[rr]);
            acci[rr] = fmaf(-j2, wki[rr], acci[rr]);
          }
        } else {
          #pragma unroll
          for (int rr = 0; rr < RPW; ++rr) {
            accr[rr] = fmaf(-sj2, wki[rr], accr[rr]);
            acci[rr] = fmaf( sj2, wkr[rr], acci[rr]);
          }
        }
      }

      if (last) {
        if (g < NG - 1) {
          publish(accr, acci);                      // psi_{g+1}
          // next gate's G rows; completes while the next wait_all spins
          const float* Gg = gens + (size_t)(g + 1) * DIM * DIM;
          #pragma unroll
          for (int rr = 0; rr < RPW; ++rr) {
            const float* Gr = Gg + (size_t)(rowbase + rr) * DIM;
            #pragma unroll
            for (int p = 0; p < 16; ++p) a[rr][p] = Gr[p * 64 + lane];
          }
        }
      } else {
        #pragma unroll
        for (int rr = 0; rr < RPW; ++rr) {
          wm2r[rr] = wm1r[rr]; wm2i[rr] = wm1i[rr];
          wm1r[rr] = wkr[rr];  wm1i[rr] = wki[rr];
        }
      }
    }
    #pragma unroll
    for (int rr = 0; rr < RPW; ++rr) { pr[rr] = accr[rr]; pi[rr] = acci[rr]; }
  }

  {
    float o = pr[0] * pr[0] + pi[0] * pi[0];
    if (lane == 1) o = pr[1] * pr[1] + pi[1] * pi[1];
    if (lane < RPW) out[rowbase + lane] = o;
  }
}

extern "C" void kernel_launch(void* const* d_in, const int* in_sizes, int n_in,
                              void* d_out, int out_size, void* d_ws, size_t ws_size,
                              hipStream_t stream) {
  const float* feat  = (const float*)d_in[0];
  const float* theta = (const float*)d_in[1];
  const float* gens  = (const float*)d_in[2];
  float* out = (float*)d_out;

  // layout: flags 64 x 64B (4KB) | vbuf0 (8KB) | vbuf1 (8KB)
  // no memset: wrap-safe compare treats the 0xAA poison as "not ready"
  unsigned* flags = (unsigned*)d_ws;
  u64* vbuf0 = (u64*)((char*)d_ws + 4096);
  u64* vbuf1 = (u64*)((char*)d_ws + 4096 + DIM * sizeof(u64));

  qsim_kernel<<<dim3(NBLK), dim3(TPB), 0, stream>>>(
      feat, theta, gens, out, vbuf0, vbuf1, flags);
}